// Round 4
// baseline (225.717 us; speedup 1.0000x reference)
//
#include <hip/hip_runtime.h>
#include <hip/hip_bf16.h>

#define B_TOT   16384
#define D_IN    784
#define H_DIM   100
#define C_DIM   10
#define HP      128
#define KP      832     // 13 * 64, padded K
#define NDR     13
#define WG_ROWS 32

typedef __bf16 bf16x8 __attribute__((ext_vector_type(8)));
typedef float  f32x4  __attribute__((ext_vector_type(4)));
typedef unsigned short u16x8 __attribute__((ext_vector_type(8)));

static __device__ __forceinline__ unsigned short f32_to_bf16(float f) {
    unsigned int u = __float_as_uint(f);
    unsigned int r = (u + 0x7FFFu + ((u >> 16) & 1u)) >> 16;
    return (unsigned short)r;
}

__global__ void prep_kernel(const float* __restrict__ W1, const float* __restrict__ b1,
                            unsigned short* __restrict__ w1hi, unsigned short* __restrict__ w1lo,
                            float* __restrict__ b1p) {
    int idx = blockIdx.x * 256 + threadIdx.x;
    if (idx < HP) b1p[idx] = (idx < H_DIM) ? b1[idx] : 0.0f;
    if (idx < HP * KP) {
        int h = idx / KP, k = idx - h * KP;
        float v = (h < H_DIM && k < D_IN) ? W1[h * D_IN + k] : 0.0f;
        unsigned short hi = f32_to_bf16(v);
        float fh = __uint_as_float(((unsigned int)hi) << 16);
        unsigned short lo = f32_to_bf16(v - fh);
        w1hi[idx] = hi;
        w1lo[idx] = lo;
    }
}

// spike pack: bit-identical arithmetic to the passing round-1 kernel
static __device__ __forceinline__ u16x8 spike8(const f32x4 i0, const f32x4 i1,
                                               const f32x4 r0, const f32x4 r1) {
    float xs[8] = {i0[0],i0[1],i0[2],i0[3],i1[0],i1[1],i1[2],i1[3]};
    float rs[8] = {r0[0],r0[1],r0[2],r0[3],r1[0],r1[1],r1[2],r1[3]};
    u16x8 v;
#pragma unroll
    for (int j = 0; j < 8; ++j) {
        unsigned short sg = xs[j] > 0.0f ? (unsigned short)0x3F80
                          : (xs[j] < 0.0f ? (unsigned short)0xBF80 : (unsigned short)0);
        v[j] = (rs[j] * 2.0f <= fabsf(xs[j])) ? sg : (unsigned short)0;
    }
    return v;
}

// raw barrier: LDS drained, VMEM loads STAY IN FLIGHT (the whole point)
#define BARRIER_KEEP_VM() asm volatile("s_waitcnt lgkmcnt(0)\n\ts_barrier" ::: "memory")

#define ISSUE_RAND(PRS, S) do { \
    const int gd_ = (S)*64 + scg*8; \
    if (gd_ + 8 <= D_IN) { \
        _Pragma("unroll") \
        for (int tt_ = 0; tt_ < 4; ++tt_) { \
            const f32x4* rp_ = reinterpret_cast<const f32x4*>(rnd + (size_t)(tp*4+tt_)*BD + inp_base + gd_); \
            PRS[tt_][0] = __builtin_nontemporal_load(rp_); \
            PRS[tt_][1] = __builtin_nontemporal_load(rp_ + 1); \
        } \
    } \
} while (0)

#define ISSUE_INP(S) do { \
    const int gd_ = (S)*64 + scg*8; \
    if (gd_ + 8 <= D_IN) { \
        const f32x4* ip_ = reinterpret_cast<const f32x4*>(inp + inp_base + gd_); \
        pii[0] = ip_[0]; pii[1] = ip_[1]; \
    } \
} while (0)

#define PACK(PRS, S, BUF) do { \
    const int gd_ = (S)*64 + scg*8; \
    const bool inb_ = (gd_ + 8 <= D_IN); \
    _Pragma("unroll") \
    for (int tt_ = 0; tt_ < 4; ++tt_) { \
        u16x8 v_ = (u16x8)0; \
        if (inb_) v_ = spike8(pii[0], pii[1], PRS[tt_][0], PRS[tt_][1]); \
        *reinterpret_cast<u16x8*>(reinterpret_cast<char*>(s_spike) + ((BUF)*4+tt_)*4096 + swByte) = v_; \
    } \
} while (0)

#define LOADB(R) do { \
    const int kb_ = (R)*64; \
    _Pragma("unroll") \
    for (int c_ = 0; c_ < 2; ++c_) \
    _Pragma("unroll") \
    for (int nt_ = 0; nt_ < 4; ++nt_) { \
        int off_ = (n_off + nt_*16 + l15)*KP + kb_ + c_*32 + l4*8; \
        bh[c_][nt_]  = *reinterpret_cast<const bf16x8*>(w1hi + off_); \
        blo[c_][nt_] = *reinterpret_cast<const bf16x8*>(w1lo + off_); \
    } \
} while (0)

#define MFMA_PHASE(BUF) do { \
    _Pragma("unroll") \
    for (int tt_ = 0; tt_ < 4; ++tt_) { \
        _Pragma("unroll") \
        for (int c_ = 0; c_ < 2; ++c_) { \
            const int g_ = (c_*4 + l4) ^ (rr & 7); \
            bf16x8 a_ = *reinterpret_cast<const bf16x8*>( \
                reinterpret_cast<const char*>(s_spike) + ((BUF)*4+tt_)*4096 + rr*128 + g_*16); \
            _Pragma("unroll") \
            for (int nt_ = 0; nt_ < 4; ++nt_) { \
                acc[tt_][nt_] = __builtin_amdgcn_mfma_f32_16x16x32_bf16(a_, bh[c_][nt_],  acc[tt_][nt_], 0,0,0); \
                acc[tt_][nt_] = __builtin_amdgcn_mfma_f32_16x16x32_bf16(a_, blo[c_][nt_], acc[tt_][nt_], 0,0,0); \
            } \
        } \
    } \
} while (0)

#define MEMUPD() do { \
    float b1v_[4]; \
    _Pragma("unroll") for (int nt_ = 0; nt_ < 4; ++nt_) b1v_[nt_] = b1p[n_off + nt_*16 + l15]; \
    _Pragma("unroll") for (int nt_ = 0; nt_ < 4; ++nt_) \
    _Pragma("unroll") for (int rg_ = 0; rg_ < 4; ++rg_) { \
        const int row_ = m_off + l4*4 + rg_, col_ = n_off + nt_*16 + l15; \
        float m_ = s_mem[row_][col_], cl_ = 0.f; \
        _Pragma("unroll") for (int tt_ = 0; tt_ < 4; ++tt_) { \
            m_ = 0.95f*m_ + acc[tt_][nt_][rg_]; \
            m_ = m_ + b1v_[nt_]; \
            float o_ = (m_ > 1.0f) ? 1.0f : 0.0f; \
            m_ -= o_; cl_ += o_; \
        } \
        s_mem[row_][col_] = m_; \
        s_cnt2[row_][col_] += cl_; \
    } \
} while (0)

// ROUND: R may be runtime; P/PN/ISLAST are literals (static reg indexing, rule #20)
#define ROUND(R, P, PN, ISLAST) do { \
    bf16x8 bh[2][4], blo[2][4]; \
    LOADB(R); \
    ISSUE_RAND(pr##P, (R)+2); \
    ISSUE_INP((R)+1); \
    MFMA_PHASE(P); \
    if (!(ISLAST)) { PACK(pr##PN, (R)+1, PN); } \
    else { MEMUPD(); } \
    BARRIER_KEEP_VM(); \
} while (0)

__global__ __launch_bounds__(256, 2)
void snn_main(const float* __restrict__ inp, const float* __restrict__ rnd,
              const unsigned short* __restrict__ w1hi, const unsigned short* __restrict__ w1lo,
              const float* __restrict__ b1p, const float* __restrict__ W2,
              const float* __restrict__ b2, float* __restrict__ out)
{
    __shared__ __align__(16) unsigned short s_spike[2 * 4 * WG_ROWS * 64]; // 32 KB dbuf
    __shared__ float s_mem[WG_ROWS][HP];    // 16 KB  (mem1 state, per-thread-private slots)
    __shared__ float s_cnt2[WG_ROWS][HP];   // 16 KB  (spike counts)

    const int tid  = threadIdx.x;
    const int lane = tid & 63;
    const int wid  = tid >> 6;
    const int m_off = (wid >> 1) * 16;
    const int n_off = (wid & 1) * 64;
    const int row0 = blockIdx.x * WG_ROWS;

    const int l15 = lane & 15;
    const int l4  = lane >> 4;
    const int rr  = m_off + l15;

    const int sr  = tid >> 3;
    const int scg = tid & 7;
    const size_t inp_base = (size_t)(row0 + sr) * D_IN;
    const int swByte = (sr * 8 + (scg ^ (sr & 7))) * 16;
    const size_t BD = (size_t)B_TOT * D_IN;

    for (int i = tid; i < WG_ROWS * HP; i += 256) {
        (&s_mem[0][0])[i] = 0.0f;
        (&s_cnt2[0][0])[i] = 0.0f;
    }
    __syncthreads();

    for (int tp = 0; tp < 2; ++tp) {
        f32x4 acc[4][4];
#pragma unroll
        for (int a_ = 0; a_ < 4; ++a_)
#pragma unroll
            for (int b_ = 0; b_ < 4; ++b_) acc[a_][b_] = (f32x4)0.0f;

        f32x4 pr0[4][2], pr1[4][2], pii[2];

        // ---- pass prologue: rand(0)->pr0, inp(0), rand(1)->pr1, pack spike(0) ----
        ISSUE_RAND(pr0, 0);
        ISSUE_INP(0);
        ISSUE_RAND(pr1, 1);
        PACK(pr0, 0, 0);
        BARRIER_KEEP_VM();

        // ---- steady state: MFMA(r) | issue rand(r+2) | pack(r+1); vmcnt never drains ----
        for (int i_ = 0; i_ < 6; ++i_) {
            ROUND(2 * i_,     0, 1, 0);
            ROUND(2 * i_ + 1, 1, 0, 0);
        }
        ROUND(12, 0, 1, 1);   // last round: MFMA + mem1/cnt state update
    }

    // ---- epilogue: counts (in s_cnt2) -> layer-2 matmul ----
    __syncthreads();
    for (int idx = tid; idx < WG_ROWS * C_DIM; idx += 256) {
        int bl_ = idx / C_DIM, c_ = idx - bl_ * C_DIM;
        float s_ = 0.0f;
        for (int h_ = 0; h_ < H_DIM; ++h_) s_ += s_cnt2[bl_][h_] * W2[c_ * H_DIM + h_];
        out[(size_t)(row0 + bl_) * C_DIM + c_] = s_ * 0.125f + b2[c_];
    }
}

extern "C" void kernel_launch(void* const* d_in, const int* in_sizes, int n_in,
                              void* d_out, int out_size, void* d_ws, size_t ws_size,
                              hipStream_t stream) {
    const float* inp = (const float*)d_in[0];
    const float* rnd = (const float*)d_in[1];
    const float* W1  = (const float*)d_in[2];
    const float* b1  = (const float*)d_in[3];
    const float* W2  = (const float*)d_in[4];
    const float* b2  = (const float*)d_in[5];
    float* out = (float*)d_out;

    unsigned short* w1hi = (unsigned short*)d_ws;
    unsigned short* w1lo = w1hi + HP * KP;
    float* b1p = (float*)(w1lo + HP * KP);

    prep_kernel<<<(HP * KP + 255) / 256, 256, 0, stream>>>(W1, b1, w1hi, w1lo, b1p);
    snn_main<<<B_TOT / WG_ROWS, 256, 0, stream>>>(inp, rnd, w1hi, w1lo, b1p, W2, b2, out);
}